// Round 1
// 699.515 us; speedup vs baseline: 2.9441x; 2.9441x over previous
//
#include <hip/hip_runtime.h>
#include <math.h>

// B=32, R=16384, C=16, IC=16, OC=16, 3 routing iterations.
// x: (B,C,IC) fp32 [8192]; W: (R,C,OC,IC) fp32 [67108864 = 256 MB]; out: (B,C,OC) fp32.
//
// Algebra note: b after iter2 = <u,v1>, after iter3 = <u,v1> + <u,v2> = <u, v1+v2>,
// so NO logit array L is needed -- both routing passes are the same kernel with a
// different v vector (v1, then v1+v2). Saves 67 MB of HBM traffic and a buffer.

#define RT 16384

#define DOT16(w0,w1,w2,w3,y0,y1,y2,y3) \
  (w0.x*y0.x + w0.y*y0.y + w0.z*y0.z + w0.w*y0.w + \
   w1.x*y1.x + w1.y*y1.y + w1.z*y1.z + w1.w*y1.w + \
   w2.x*y2.x + w2.y*y2.y + w2.z*y2.z + w2.w*y2.w + \
   w3.x*y3.x + w3.y*y3.y + w3.z*y3.z + w3.w*y3.w)

// async global->LDS, 16 B per lane. LDS dest = wave-uniform base + lane*16.
__device__ __forceinline__ void gload_lds16(const void* g, void* l) {
  __builtin_amdgcn_global_load_lds(
      (const __attribute__((address_space(1))) unsigned int*)g,
      (__attribute__((address_space(3))) unsigned int*)l, 16, 0, 0);
}

__device__ __forceinline__ float rfl(float v) {
  return __uint_as_float(__builtin_amdgcn_readfirstlane(__float_as_uint(v)));
}

// ---------------------------------------------------------------------------
// K1: wsum[c,o,i] = sum_r W[r,c,o,i].  W = 16,777,216 float4s.
// ---------------------------------------------------------------------------
__global__ __launch_bounds__(256) void k_wsum(const float4* __restrict__ W4,
                                              float* __restrict__ wsum) {
    int gid = blockIdx.x * 256 + threadIdx.x;      // [0, 262144)
    float4 acc = {0.f, 0.f, 0.f, 0.f};
    int idx = gid;
    #pragma unroll
    for (int it = 0; it < 64; ++it) {              // 16777216 / 262144 = 64
        float4 w = W4[idx];
        acc.x += w.x; acc.y += w.y; acc.z += w.z; acc.w += w.w;
        idx += 262144;
    }
    int cls = gid & 1023;                          // (c,o,i4) within an r-block
    atomicAdd(&wsum[cls * 4 + 0], acc.x);
    atomicAdd(&wsum[cls * 4 + 1], acc.y);
    atomicAdd(&wsum[cls * 4 + 2], acc.z);
    atomicAdd(&wsum[cls * 4 + 3], acc.w);
}

// ---------------------------------------------------------------------------
// K2: s1 = (1/R) * wsum . x ;  v1 = squash(s1)  -> v1[b*256 + c*16 + o]
// ---------------------------------------------------------------------------
__global__ __launch_bounds__(256) void k_v1(const float* __restrict__ wsum,
                                            const float* __restrict__ x,
                                            float* __restrict__ v1) {
    int t = blockIdx.x * 256 + threadIdx.x;        // 0..8191
    int o = t & 15, c = (t >> 4) & 15, b = t >> 8;
    const float* xb = x + (b * 16 + c) * 16;
    const float* wr = wsum + (c * 16 + o) * 16;
    float s = 0.f;
    #pragma unroll
    for (int i = 0; i < 16; ++i) s += wr[i] * xb[i];
    s *= (1.0f / 16384.0f);
    float ns = s * s;
    #pragma unroll
    for (int d = 1; d < 16; d <<= 1) ns += __shfl_xor(ns, d);
    v1[t] = s * (sqrtf(ns) / (1.0f + ns));
}

// ---------------------------------------------------------------------------
// k_vsum: v2 = squash(E/Z); vsum = v1 + v2   (dot vector for pass 3)
// ---------------------------------------------------------------------------
__global__ __launch_bounds__(256) void k_vsum(const float* __restrict__ E,
                                              const float* __restrict__ Z,
                                              const float* __restrict__ v1,
                                              float* __restrict__ vsum) {
    int t = blockIdx.x * 256 + threadIdx.x;        // 0..8191
    float s = E[t] / Z[t >> 4];
    float ns = s * s;
    #pragma unroll
    for (int d = 1; d < 16; d <<= 1) ns += __shfl_xor(ns, d);
    vsum[t] = v1[t] + s * (sqrtf(ns) / (1.0f + ns));
}

// ---------------------------------------------------------------------------
// k_vout: final v = squash(E/Z) -> out
// ---------------------------------------------------------------------------
__global__ __launch_bounds__(256) void k_vout(const float* __restrict__ E,
                                              const float* __restrict__ Z,
                                              float* __restrict__ dst) {
    int t = blockIdx.x * 256 + threadIdx.x;        // 0..8191
    float s = E[t] / Z[t >> 4];
    float ns = s * s;
    #pragma unroll
    for (int d = 1; d < 16; d <<= 1) ns += __shfl_xor(ns, d);
    dst[t] = s * (sqrtf(ns) / (1.0f + ns));
}

// ---------------------------------------------------------------------------
// k_route: one routing pass.  For each (b,c,r):
//   u[o]  = sum_i W[r,c,o,i] * x[b,c,i]
//   e     = exp(sum_o u[o]*v[b,c,o])      (|L|<=~60, safe in fp32)
//   E[b,c,o] += e*u[o];  Z[b,c] += e
// Block 512 = 8 waves; wave wv owns b in {4wv..4wv+3}; lane = r within the
// 64-row chunk; 4 chunks per block, double-buffered 2x64KB LDS staged with
// global_load_lds (source pre-swizzled, LDS linear).  Grid (64,16).
// __launch_bounds__(512,1): 256-VGPR budget -> no scratch spills (the previous
// version at (512,2)/128 VGPR spilled ~90 regs = ~1 GB/pass scratch traffic).
// v is wave-uniform per (b,c) -> SGPRs via readfirstlane (saves 64 VGPRs).
// ---------------------------------------------------------------------------
__global__ __launch_bounds__(512, 1) void k_route(const float* __restrict__ W,
                                                  const float* __restrict__ x,
                                                  const float* __restrict__ v,
                                                  float* __restrict__ E,
                                                  float* __restrict__ Z) {
    __shared__ float4 Wl[2][64 * 64];              // 128 KB double buffer
    const int c = blockIdx.y;
    const int r0 = blockIdx.x * 256;
    const int tid = threadIdx.x;
    const int wv = __builtin_amdgcn_readfirstlane(tid >> 6);
    const int lane = tid & 63;

    const float4* W4c = (const float4*)W + c * 64; // + r*1024 + j

    // x rows for this wave's 4 b's (VGPR), v rows in SGPRs (wave-uniform)
    float4 xr[4][4];
    float vs[4][16];
    #pragma unroll
    for (int bl = 0; bl < 4; ++bl) {
        const float4* xb = (const float4*)(x + ((wv * 4 + bl) * 16 + c) * 16);
        const float*  vb = v + ((wv * 4 + bl) * 16 + c) * 16;
        xr[bl][0] = xb[0]; xr[bl][1] = xb[1]; xr[bl][2] = xb[2]; xr[bl][3] = xb[3];
        #pragma unroll
        for (int o = 0; o < 16; ++o) vs[bl][o] = rfl(vb[o]);
    }

    float accE[4][16];
    float accZ[4] = {0.f, 0.f, 0.f, 0.f};
    #pragma unroll
    for (int bl = 0; bl < 4; ++bl)
        #pragma unroll
        for (int o = 0; o < 16; ++o) accE[bl][o] = 0.f;

    // stage chunk 0: wave wv stages rows {k*8+wv}; lane l writes slot rl*64+l,
    // so the global source is pre-swizzled: float4 (l ^ rl) of the row.
    #pragma unroll
    for (int k = 0; k < 8; ++k) {
        int rl = k * 8 + wv;
        gload_lds16(W4c + (size_t)(r0 + rl) * 1024 + (lane ^ rl), &Wl[0][rl * 64]);
    }
    __syncthreads();                               // drains vmcnt(0)

    #pragma unroll
    for (int ch = 0; ch < 4; ++ch) {
        if (ch < 3) {                              // issue next chunk's loads first
            #pragma unroll
            for (int k = 0; k < 8; ++k) {
                int rl = k * 8 + wv;
                gload_lds16(W4c + (size_t)(r0 + (ch + 1) * 64 + rl) * 1024 + (lane ^ rl),
                            &Wl[(ch + 1) & 1][rl * 64]);
            }
        }
        const float4* Wb = Wl[ch & 1];

        float u[4][16];
        #pragma unroll
        for (int o = 0; o < 16; ++o) {
            float4 w0 = Wb[lane * 64 + ((o * 4 + 0) ^ lane)];
            float4 w1 = Wb[lane * 64 + ((o * 4 + 1) ^ lane)];
            float4 w2 = Wb[lane * 64 + ((o * 4 + 2) ^ lane)];
            float4 w3 = Wb[lane * 64 + ((o * 4 + 3) ^ lane)];
            #pragma unroll
            for (int bl = 0; bl < 4; ++bl)
                u[bl][o] = DOT16(w0, w1, w2, w3,
                                 xr[bl][0], xr[bl][1], xr[bl][2], xr[bl][3]);
        }

        #pragma unroll
        for (int bl = 0; bl < 4; ++bl) {
            float Lv = 0.f;
            #pragma unroll
            for (int o = 0; o < 16; ++o) Lv += u[bl][o] * vs[bl][o];
            float e = __expf(Lv);
            accZ[bl] += e;
            #pragma unroll
            for (int o = 0; o < 16; ++o) accE[bl][o] += e * u[bl][o];
        }
        __syncthreads();   // barrier + vmcnt(0) drain of loads issued pre-compute
    }

    // Butterfly-reduce the 64 accE values + 4 accZ over the 64 lanes.
    float va = 0.f;
    #pragma unroll
    for (int bl = 0; bl < 4; ++bl) {
        #pragma unroll
        for (int o = 0; o < 16; ++o) {
            float t = accE[bl][o];
            #pragma unroll
            for (int d = 1; d < 64; d <<= 1) t += __shfl_xor(t, d);
            if (lane == bl * 16 + o) va = t;
        }
    }
    float vz = 0.f;
    #pragma unroll
    for (int bl = 0; bl < 4; ++bl) {
        float t = accZ[bl];
        #pragma unroll
        for (int d = 1; d < 64; d <<= 1) t += __shfl_xor(t, d);
        if (lane == bl) vz = t;
    }
    int b = wv * 4 + (lane >> 4);
    atomicAdd(&E[b * 256 + c * 16 + (lane & 15)], va);
    if (lane < 4) atomicAdd(&Z[(wv * 4 + lane) * 16 + c], vz);
}

// ---------------------------------------------------------------------------
// launch
// ---------------------------------------------------------------------------
extern "C" void kernel_launch(void* const* d_in, const int* in_sizes, int n_in,
                              void* d_out, int out_size, void* d_ws, size_t ws_size,
                              hipStream_t stream) {
    const float* x = (const float*)d_in[0];        // 8192 floats
    const float* W = (const float*)d_in[1];        // 67108864 floats (256 MB)
    float* out = (float*)d_out;                    // 8192 floats
    float* ws = (float*)d_ws;

    float* wsum = ws + 0;          // 4096
    float* E2   = ws + 4096;       // 8192
    float* Z2   = ws + 12288;      // 512
    float* E3   = ws + 12800;      // 8192
    float* Z3   = ws + 20992;      // 512   (zeroed region ends at 21504)
    float* v1   = ws + 21504;      // 8192
    float* vsum = ws + 29696;      // 8192

    hipMemsetAsync(ws, 0, 21504 * sizeof(float), stream);

    // iter 1: uniform softmax -> v1 from Wsum (W pass 1)
    k_wsum<<<1024, 256, 0, stream>>>((const float4*)W, wsum);
    k_v1<<<32, 256, 0, stream>>>(wsum, x, v1);

    // iter 2: logits = <u, v1>  (W pass 2)
    k_route<<<dim3(64, 16), 512, 0, stream>>>(W, x, v1, E2, Z2);
    k_vsum<<<32, 256, 0, stream>>>(E2, Z2, v1, vsum);  // vsum = v1 + squash(E2/Z2)

    // iter 3: logits = <u, v1+v2>  (W pass 3)
    k_route<<<dim3(64, 16), 512, 0, stream>>>(W, x, vsum, E3, Z3);
    k_vout<<<32, 256, 0, stream>>>(E3, Z3, out);
}